// Round 12
// baseline (284.506 us; speedup 1.0000x reference)
//
#include <hip/hip_runtime.h>
#include <hip/hip_bf16.h>

// MHA block: B=2, S=2048, D=1024, H=16, DK=64, causal. fp32 in/out.
// ROUND 21: delete the q/k/v conversion pass. cvt7 was ~25us of pure
// overhead (96MB read + 48MB write that gemm immediately re-reads).
// Now: cvt_w converts weights only (~6us); gemm_qkv5 reads A as fp32 and
// reg-stages it (f32x4 loads -> cvt_pk -> ds_write_b128); W keeps async
// gld16 from pre-converted bf16. LDS stays 24KB. Fragment path untouched.
// attn_fwd11 (r17 best, 75.7us), gemm_out (r19 64x64) unchanged.

typedef __bf16 bf16_t;
typedef __bf16 bf16x4 __attribute__((ext_vector_type(4)));
typedef __bf16 bf16x8 __attribute__((ext_vector_type(8)));
typedef float f32x4 __attribute__((ext_vector_type(4)));

#define BB 2
#define SS 2048
#define DD 1024
#define HH 16
#define DKK 64
#define MM 4096            // tokens = B*S

#define NELT ((size_t)BB * SS * DD)     // 4,194,304
#define WELT ((size_t)DD * DD)          // 1,048,576

// layout: Qp | Kp | Vt | Xa | Wqb | Wkb | Wvb | Wob
__device__ __align__(16) bf16_t g_ws[4 * NELT + 4 * WELT];

// async global->LDS, 16 B/lane; LDS dest = wave-uniform base + lane*16
__device__ __forceinline__ void gld16(const bf16_t* g, bf16_t* l) {
    __builtin_amdgcn_global_load_lds(
        (const __attribute__((address_space(1))) void*)g,
        (__attribute__((address_space(3))) void*)l, 16, 0, 0);
}

// ---------------------------------------------------------------------------
// fp32 -> bf16 pre-convert, WEIGHTS ONLY (4 x 1M elements)
// ---------------------------------------------------------------------------
__global__ __launch_bounds__(256) void cvt_w(
    const float* __restrict__ Wq, const float* __restrict__ Wk,
    const float* __restrict__ Wv, const float* __restrict__ Wo,
    bf16_t* __restrict__ Wqb, bf16_t* __restrict__ Wkb,
    bf16_t* __restrict__ Wvb, bf16_t* __restrict__ Wob)
{
    const float* s; bf16_t* d;
    switch (blockIdx.y) {
        case 0:  s = Wq; d = Wqb; break;
        case 1:  s = Wk; d = Wkb; break;
        case 2:  s = Wv; d = Wvb; break;
        default: s = Wo; d = Wob; break;
    }
    size_t e = ((size_t)blockIdx.x * 256 + threadIdx.x) * 8;
    if (e >= WELT) return;
    f32x4 a = *(const f32x4*)(s + e);
    f32x4 b = *(const f32x4*)(s + e + 4);
    bf16x8 o;
    #pragma unroll
    for (int i = 0; i < 4; ++i) { o[i] = (bf16_t)a[i]; o[4 + i] = (bf16_t)b[i]; }
    *(bf16x8*)(d + e) = o;
}

// ---------------------------------------------------------------------------
// Fused QKV projection: BM=64, BN=128, BK=64 -> grid (64,8,3)=1536 blocks.
// A read DIRECTLY as fp32 (reg-staged + converted); W async gld16 (bf16).
// z=0: Qp=(q@Wq^T+bq)*(0.125*log2e) ; z=1: Kp ; z=2: Vt (transposed store)
// XCD swizzle: XCD k owns x in [8k,8k+8) for all y (A-panel L2 locality;
// fp32 panels: 8 x 256KB = 2MB per XCD, L2-resident).
// ---------------------------------------------------------------------------
#define BMQ 64
#define BNQ 128
#define BKG 64
#define LDCQ 68

__global__ __launch_bounds__(256) void gemm_qkv5(
    const float* __restrict__ qf32, const float* __restrict__ kf32, const float* __restrict__ vf32,
    const bf16_t* __restrict__ Wqb, const bf16_t* __restrict__ Wkb, const bf16_t* __restrict__ Wvb,
    const float* __restrict__ bq, const float* __restrict__ bk, const float* __restrict__ bv,
    bf16_t* __restrict__ Qp, bf16_t* __restrict__ Kp, bf16_t* __restrict__ Vt)
{
    const int z = blockIdx.z;
    const float*  A    = (z == 0) ? qf32 : (z == 1) ? kf32 : vf32;
    const bf16_t* W    = (z == 0) ? Wqb  : (z == 1) ? Wkb  : Wvb;
    const float*  bias = (z == 0) ? bq   : (z == 1) ? bk   : bv;

    // union: As[64][64] (8KB) + Bs[128][64] (16KB) = 24KB vs Ct[128][68] 17.4KB
    __shared__ __align__(16) bf16_t smem[(BMQ + BNQ) * BKG];
    bf16_t (*As)[BKG]  = (bf16_t(*)[BKG])smem;
    bf16_t (*Bs)[BKG]  = (bf16_t(*)[BKG])(smem + BMQ * BKG);
    bf16_t (*Ct)[LDCQ] = (bf16_t(*)[LDCQ])smem;

    const int tid  = threadIdx.x;
    const int wave = tid >> 6;
    const int lane = tid & 63;
    const int quad = lane >> 4;
    const int c16  = lane & 15;

    // XCD-aware remap: f = per-slice dispatch id (x fastest, 512 wgs).
    // f2 = (f%8)*64 + f/8 -> XCD k gets f2 in [64k,64k+64):
    // x = f2>>3 in [8k,8k+8) (A panels), y = f2&7.
    const int f  = blockIdx.x + 64 * blockIdx.y;
    const int f2 = (f & 7) * 64 + (f >> 3);
    const int bm = (f2 >> 3) * BMQ;
    const int bn = (f2 & 7) * BNQ;

    const int wm = (wave >> 1) * 32;
    const int wn = (wave & 1) * 64;

    const int srow = lane >> 3;        // 0..7 within an 8-row chunk
    const int scol = (lane & 7) * 8;   // 0..56

    f32x4 acc[2][4] = {};

    for (int k0 = 0; k0 < DD; k0 += BKG) {
        __syncthreads();
        // A: fp32 -> bf16 reg-staged, 2 chunks of 8 rows per wave
        #pragma unroll
        for (int j = 0; j < 2; ++j) {
            int r0 = wave * 16 + j * 8;
            const float* ap = A + (size_t)(bm + r0 + srow) * DD + k0 + scol;
            f32x4 x = *(const f32x4*)ap;
            f32x4 y = *(const f32x4*)(ap + 4);
            bf16x8 o;
            #pragma unroll
            for (int i = 0; i < 4; ++i) { o[i] = (bf16_t)x[i]; o[4 + i] = (bf16_t)y[i]; }
            *(bf16x8*)(&As[r0 + srow][scol]) = o;
        }
        // W: async DMA, 4 chunks of 8 rows per wave
        #pragma unroll
        for (int j = 0; j < 4; ++j) {
            int r0 = wave * 32 + j * 8;
            gld16(W + (size_t)(bn + r0 + srow) * DD + k0 + scol, &Bs[r0][0]);
        }
        __syncthreads();   // drains vmcnt/lgkmcnt -> staging complete

        #pragma unroll
        for (int ks = 0; ks < 2; ++ks) {
            bf16x8 af[2], bfr[4];
            #pragma unroll
            for (int tm = 0; tm < 2; ++tm)
                af[tm] = *(const bf16x8*)(&As[wm + tm * 16 + c16][ks * 32 + quad * 8]);
            #pragma unroll
            for (int tn = 0; tn < 4; ++tn)
                bfr[tn] = *(const bf16x8*)(&Bs[wn + tn * 16 + c16][ks * 32 + quad * 8]);
            #pragma unroll
            for (int tm = 0; tm < 2; ++tm)
                #pragma unroll
                for (int tn = 0; tn < 4; ++tn)
                    acc[tm][tn] = __builtin_amdgcn_mfma_f32_16x16x32_bf16(
                        af[tm], bfr[tn], acc[tm][tn], 0, 0, 0);
        }
    }

    float bia[4];
    #pragma unroll
    for (int tn = 0; tn < 4; ++tn)
        bia[tn] = bias[bn + wn + tn * 16 + c16];

    if (z < 2) {
        // Q carries 1/sqrt(DK) * log2(e) so attention can use exp2
        const float osc = (z == 0) ? 0.125f * 1.4426950408889634f : 1.0f;
        bf16_t* C = (z == 0) ? Qp : Kp;
        #pragma unroll
        for (int tm = 0; tm < 2; ++tm)
            #pragma unroll
            for (int r = 0; r < 4; ++r) {
                size_t base = (size_t)(bm + wm + tm * 16 + quad * 4 + r) * DD;
                #pragma unroll
                for (int tn = 0; tn < 4; ++tn)
                    C[base + bn + wn + tn * 16 + c16] =
                        (bf16_t)((acc[tm][tn][r] + bia[tn]) * osc);
            }
    } else {
        __syncthreads();
        #pragma unroll
        for (int tm = 0; tm < 2; ++tm)
            #pragma unroll
            for (int tn = 0; tn < 4; ++tn) {
                bf16x4 pk;
                #pragma unroll
                for (int r = 0; r < 4; ++r)
                    pk[r] = (bf16_t)(acc[tm][tn][r] + bia[tn]);
                *(bf16x4*)(&Ct[wn + tn * 16 + c16][wm + tm * 16 + quad * 4]) = pk;
            }
        __syncthreads();
        const int b_    = bm >> 11;
        const int sbase = bm & (SS - 1);
        #pragma unroll
        for (int p = 0; p < 4; ++p) {
            int col = p * 32 + (tid >> 3);       // 0..127
            int si  = (tid & 7) * 8;             // 0..56 (64-wide stripe)
            size_t rowoff = (size_t)(b_ * 1024 + bn + col) * SS + sbase;
            *(bf16x8*)(&Vt[rowoff + si]) = *(const bf16x8*)(&Ct[col][si]);
        }
    }
}

// ---------------------------------------------------------------------------
// Output projection: BM=64, BN=64, BK=64 -> grid (64,16)=1024 blocks
// (4 blocks/CU, 16 waves/CU). Wave tile 32x32. XCD swizzle: XCD k owns
// x in [8k,8k+8) for all y (A-panel locality).
// ---------------------------------------------------------------------------
__global__ __launch_bounds__(256) void gemm_out(
    const bf16_t* __restrict__ A,    // Xa [M,K]
    const bf16_t* __restrict__ W,    // Wob [N,K]
    const float* __restrict__ bias,
    float* __restrict__ C)
{
    __shared__ __align__(16) bf16_t As[64][BKG];
    __shared__ __align__(16) bf16_t Bs[64][BKG];

    const int tid  = threadIdx.x;
    const int wave = tid >> 6;
    const int lane = tid & 63;
    const int quad = lane >> 4;
    const int c16  = lane & 15;

    // f = dispatch id (x fastest, 1024 wgs). f2 = (f%8)*128 + f/8:
    // XCD k gets f2 in [128k,128k+128): x = f2>>4 in [8k,8k+8), y = f2&15.
    const int f  = blockIdx.x + 64 * blockIdx.y;
    const int f2 = (f & 7) * 128 + (f >> 3);
    const int bm = (f2 >> 4) * 64;
    const int bn = (f2 & 15) * 64;

    const int wm = (wave >> 1) * 32;
    const int wn = (wave & 1) * 32;

    const int srow = lane >> 3;
    const int scol = (lane & 7) * 8;

    f32x4 acc[2][2] = {};

    for (int k0 = 0; k0 < DD; k0 += BKG) {
        __syncthreads();
        #pragma unroll
        for (int j = 0; j < 2; ++j) {
            int r0 = wave * 16 + j * 8;
            gld16(A + (size_t)(bm + r0 + srow) * DD + k0 + scol, &As[r0][0]);
            gld16(W + (size_t)(bn + r0 + srow) * DD + k0 + scol, &Bs[r0][0]);
        }
        __syncthreads();

        #pragma unroll
        for (int ks = 0; ks < 2; ++ks) {
            bf16x8 af[2], bfr[2];
            #pragma unroll
            for (int tm = 0; tm < 2; ++tm)
                af[tm] = *(const bf16x8*)(&As[wm + tm * 16 + c16][ks * 32 + quad * 8]);
            #pragma unroll
            for (int tn = 0; tn < 2; ++tn)
                bfr[tn] = *(const bf16x8*)(&Bs[wn + tn * 16 + c16][ks * 32 + quad * 8]);
            #pragma unroll
            for (int tm = 0; tm < 2; ++tm)
                #pragma unroll
                for (int tn = 0; tn < 2; ++tn)
                    acc[tm][tn] = __builtin_amdgcn_mfma_f32_16x16x32_bf16(
                        af[tm], bfr[tn], acc[tm][tn], 0, 0, 0);
        }
    }

    float bia[2];
    #pragma unroll
    for (int tn = 0; tn < 2; ++tn)
        bia[tn] = bias[bn + wn + tn * 16 + c16];

    #pragma unroll
    for (int tm = 0; tm < 2; ++tm)
        #pragma unroll
        for (int r = 0; r < 4; ++r) {
            size_t base = (size_t)(bm + wm + tm * 16 + quad * 4 + r) * DD;
            #pragma unroll
            for (int tn = 0; tn < 2; ++tn)
                C[base + bn + wn + tn * 16 + c16] = acc[tm][tn][r] + bia[tn];
        }
}

// ---------------------------------------------------------------------------
// Split-K flash attention (r17 structure, unchanged), paired qtiles.
// Grid = dim3(1024): bh = (id%8)*4 + id/256 (XCD-resident), pair = (id>>3)&31.
// ---------------------------------------------------------------------------
#define LDPS 40   // P row stride (bf16): rows=q(32), cols=key(32)
#define LDCF 68   // combine row stride (fp32)

#define LOADK(KF, UU)                                                          \
do {                                                                           \
    const int kb_ = (UU) * 32;                                                 \
    const bf16_t* kp0 = Kb + (size_t)(kb_ + c16) * DD;                         \
    const bf16_t* kp1 = Kb + (size_t)(kb_ + 16 + c16) * DD;                    \
    KF[0][0] = *(const bf16x8*)(kp0 + quad * 8);                               \
    KF[0][1] = *(const bf16x8*)(kp0 + 32 + quad * 8);                          \
    KF[1][0] = *(const bf16x8*)(kp1 + quad * 8);                               \
    KF[1][1] = *(const bf16x8*)(kp1 + 32 + quad * 8);                          \
} while (0)

// r12-style step: QK[u] on KFC | prefetch K[u+4]->KFN | load V[u] | exp2 +
// packed P store | lgkmcnt(0) | PV[u] same step.
#define ATTN_STEP(UU, KFC, KFN)                                                \
do {                                                                           \
    const int kb_ = (UU) * 32;                                                 \
    f32x4 sc_[2][2];                                                           \
    __builtin_amdgcn_s_setprio(1);                                             \
    _Pragma("unroll")                                                          \
    for (int tm = 0; tm < 2; ++tm)                                             \
        _Pragma("unroll")                                                      \
        for (int ct = 0; ct < 2; ++ct) {                                       \
            f32x4 s_ = {};                                                     \
            s_ = __builtin_amdgcn_mfma_f32_16x16x32_bf16(                      \
                     KFC[ct][0], qf[tm][0], s_, 0, 0, 0);                      \
            s_ = __builtin_amdgcn_mfma_f32_16x16x32_bf16(                      \
                     KFC[ct][1], qf[tm][1], s_, 0, 0, 0);                      \
            sc_[tm][ct] = s_;                                                  \
        }                                                                      \
    __builtin_amdgcn_s_setprio(0);                                             \
    if ((UU) + 4 < U) LOADK(KFN, (UU) + 4);                                    \
    bf16x8 vf_[4];                                                             \
    _Pragma("unroll")                                                          \
    for (int tn = 0; tn < 4; ++tn)                                             \
        vf_[tn] = *(const bf16x8*)(Vb + (size_t)(tn * 16 + c16) * SS           \
                                   + kb_ + quad * 8);                          \
    const bool needmask_ = (kb_ == qbase);                                     \
    _Pragma("unroll")                                                          \
    for (int tm = 0; tm < 2; ++tm) {                                           \
        const int qrow_ = qbase + tm * 16 + c16;                               \
        _Pragma("unroll")                                                      \
        for (int ct = 0; ct < 2; ++ct) {                                       \
            bf16x4 w_;                                                         \
            _Pragma("unroll")                                                  \
            for (int r = 0; r < 4; ++r) {                                      \
                float s_ = sc_[tm][ct][r];                                     \
                if (needmask_ && (kb_ + ct * 16 + quad * 4 + r > qrow_))       \
                    s_ = -1e9f;                                                \
                float p_ = __builtin_amdgcn_exp2f(s_);                         \
                lsum2[tm] += p_;                                               \
                w_[r] = (bf16_t)p_;                                            \
            }                                                                  \
            *(bf16x4*)(pw + tm * 16 * LDPS + ct * 16) = w_;                    \
        }                                                                      \
    }                                                                          \
    asm volatile("s_waitcnt lgkmcnt(0)" ::: "memory");                         \
    __builtin_amdgcn_s_setprio(1);                                             \
    _Pragma("unroll")                                                          \
    for (int tm = 0; tm < 2; ++tm) {                                           \
        bf16x8 pa_ = *(const bf16x8*)(pr + tm * 16 * LDPS);                    \
        _Pragma("unroll")                                                      \
        for (int tn = 0; tn < 4; ++tn)                                         \
            oacc[tm][tn] = __builtin_amdgcn_mfma_f32_16x16x32_bf16(            \
                pa_, vf_[tn], oacc[tm][tn], 0, 0, 0);                          \
    }                                                                          \
    __builtin_amdgcn_s_setprio(0);                                             \
} while (0)

__global__ __launch_bounds__(256) void attn_fwd11(
    const bf16_t* __restrict__ Q,   // [B,S,D] (pre-scaled by 0.125*log2e)
    const bf16_t* __restrict__ K,   // [B,S,D]
    const bf16_t* __restrict__ Vt,  // [(b*1024 + h*64 + dk)][s]
    bf16_t* __restrict__ O)         // [B,S,D]
{
    const int flat = blockIdx.x;
    const int bh   = (flat & 7) * 4 + (flat >> 8);   // XCD-resident heads
    const int pair = (flat >> 3) & 31;
    const int b = bh >> 4;
    const int h = bh & 15;

    const int wave = threadIdx.x >> 6;
    const int lane = threadIdx.x & 63;
    const int quad = lane >> 4;
    const int c16  = lane & 15;

    // union: Ps[4][32][LDPS] bf16 (10.2 KB) / Cf[4][16][LDCF] fp32 (17.4 KB)
    __shared__ __align__(16) unsigned char smraw[4 * 16 * LDCF * 4];
    bf16_t (*Ps)[32][LDPS] = (bf16_t(*)[32][LDPS])smraw;
    float  (*Cf)[16][LDCF] = (float(*)[16][LDCF])smraw;
    __shared__ float Ls[4][32];

    const bf16_t* Kb = K  + (size_t)b * SS * DD + h * DKK;
    const bf16_t* Vb = Vt + (size_t)(b * 1024 + h * DKK) * SS;

    // fixed per-lane LDS addresses (immediate offsets inside the loop)
    bf16_t*       pw = &Ps[wave][c16][quad * 4];   // + tm*16*LDPS + ct*16
    const bf16_t* pr = &Ps[wave][c16][quad * 8];   // + tm*16*LDPS

    for (int t = 0; t < 2; ++t) {
        const int qt    = (t == 0) ? (63 - pair) : pair;   // heavy tile first
        const int qbase = qt * 32;
        const int U     = qt + 1;          // 32-key units

        // Q fragments (B operand of swapped MFMA): rows qbase..qbase+31
        bf16x8 qf[2][2];
        #pragma unroll
        for (int tm = 0; tm < 2; ++tm) {
            const bf16_t* qp = Q + ((size_t)b * SS + qbase + tm * 16 + c16) * DD + h * DKK;
            qf[tm][0] = *(const bf16x8*)(qp + quad * 8);
            qf[tm][1] = *(const bf16x8*)(qp + 32 + quad * 8);
        }

        f32x4 oacc[2][4] = {};
        float lsum2[2] = {0.f, 0.f};

        bf16x8 kfA[2][2], kfB[2][2];   // K fragment double buffer [ct][kstep]

        {
            int u = wave;
            if (u < U) {
                LOADK(kfA, u);
                for (;;) {
                    ATTN_STEP(u, kfA, kfB); u += 4;
                    if (u >= U) break;
                    ATTN_STEP(u, kfB, kfA); u += 4;
                    if (u >= U) break;
                }
            }
        }

        // ---- per-wave row sums (reduce over quads) -> Ls ----
        #pragma unroll
        for (int tm = 0; tm < 2; ++tm) {
            float l = lsum2[tm];
            l += __shfl_xor(l, 16, 64);
            l += __shfl_xor(l, 32, 64);
            if (lane < 16) Ls[wave][tm * 16 + lane] = l;
        }

        // ---- combine partials: two tm-passes through Cf (aliases Ps) ----
        const int row = threadIdx.x >> 4;        // 0..15
        const int col = (threadIdx.x & 15) * 4;  // 0..60
        #pragma unroll
        for (int tm = 0; tm < 2; ++tm) {
            __syncthreads();   // tm=0: unit loops done (Ps free); tm=1: pass-0 reads done
            #pragma unroll
            for (int tn = 0; tn < 4; ++tn)
                #pragma unroll
                for (int r = 0; r < 4; ++r)
                    Cf[wave][quad * 4 + r][tn * 16 + c16] = oacc[tm][tn][r];
            __syncthreads();
            f32x4 ssum = {};
            #pragma unroll
            for (int p = 0; p < 4; ++p)
                ssum += *(const f32x4*)(&Cf[p][row][col]);
            float l = Ls[0][tm * 16 + row] + Ls[1][tm * 16 + row]
                    + Ls[2][tm * 16 + row] + Ls[3][tm * 16 + row];
            float inv = 1.0f / l;
            bf16x4 o;
            #pragma unroll
            for (int i = 0; i < 4; ++i) o[i] = (bf16_t)(ssum[i] * inv);
            *(bf16x4*)(&O[((size_t)b * SS + qbase + tm * 16 + row) * DD + h * DKK + col]) = o;
        }
        __syncthreads();   // tile end: Ps/Cf/Ls reusable by next tile
    }
}

// ---------------------------------------------------------------------------
extern "C" void kernel_launch(void* const* d_in, const int* in_sizes, int n_in,
                              void* d_out, int out_size, void* d_ws, size_t ws_size,
                              hipStream_t stream) {
    (void)in_sizes; (void)n_in; (void)out_size; (void)d_ws; (void)ws_size;
    const float* q  = (const float*)d_in[0];
    const float* k  = (const float*)d_in[1];
    const float* v  = (const float*)d_in[2];
    const float* Wq = (const float*)d_in[4];
    const float* bq = (const float*)d_in[5];
    const float* Wk = (const float*)d_in[6];
    const float* bk = (const float*)d_in[7];
    const float* Wv = (const float*)d_in[8];
    const float* bv = (const float*)d_in[9];
    const float* Wo = (const float*)d_in[10];
    const float* bo = (const float*)d_in[11];

    bf16_t* ws;
    hipGetSymbolAddress((void**)&ws, HIP_SYMBOL(g_ws));
    bf16_t* Qp  = ws;
    bf16_t* Kp  = Qp + NELT;
    bf16_t* Vt  = Kp + NELT;
    bf16_t* Xa  = Vt + NELT;
    bf16_t* Wqb = Xa + NELT;
    bf16_t* Wkb = Wqb + WELT;
    bf16_t* Wvb = Wkb + WELT;
    bf16_t* Wob = Wvb + WELT;

    cvt_w<<<dim3(512, 4), 256, 0, stream>>>(Wq, Wk, Wv, Wo,
                                            Wqb, Wkb, Wvb, Wob);

    gemm_qkv5<<<dim3(MM / BMQ, DD / BNQ, 3), 256, 0, stream>>>(
        q, k, v, Wqb, Wkb, Wvb, bq, bk, bv, Qp, Kp, Vt);

    attn_fwd11<<<dim3(1024), 256, 0, stream>>>(Qp, Kp, Vt, Xa);

    gemm_out<<<dim3(64, 16), 256, 0, stream>>>(Xa, Wob, bo, (float*)d_out);
}

// Round 13
// 268.607 us; speedup vs baseline: 1.0592x; 1.0592x over previous
//
#include <hip/hip_runtime.h>
#include <hip/hip_bf16.h>

// MHA block: B=2, S=2048, D=1024, H=16, DK=64, causal. fp32 in/out.
// ROUND 22: fix r21's fused gemm_qkv5 using its first-ever counters:
// 14.2M LDS bank conflicts (8-way on the A reg-staging ds_write_b128 --
// row stride 128B) + serial load->cvt->write->barrier chain (VALUBusy 9%).
//  - T2 XOR-swizzle on As: write AND read elem ^= (row&7)<<3 (legal:
//    reg-staged, not DMA; rule #21). Write spreads 8 bank groups; frag
//    read becomes 2-way (free).
//  - T14 split: A(k+1) fp32 loads issue right after the compute barrier,
//    overlapping the MFMA phase; consumed at next iter's write.
// cvt_w (weights only), attn_fwd11 (r17 best), gemm_out (r19) unchanged.

typedef __bf16 bf16_t;
typedef __bf16 bf16x4 __attribute__((ext_vector_type(4)));
typedef __bf16 bf16x8 __attribute__((ext_vector_type(8)));
typedef float f32x4 __attribute__((ext_vector_type(4)));

#define BB 2
#define SS 2048
#define DD 1024
#define HH 16
#define DKK 64
#define MM 4096            // tokens = B*S

#define NELT ((size_t)BB * SS * DD)     // 4,194,304
#define WELT ((size_t)DD * DD)          // 1,048,576

// layout: Qp | Kp | Vt | Xa | Wqb | Wkb | Wvb | Wob
__device__ __align__(16) bf16_t g_ws[4 * NELT + 4 * WELT];

// async global->LDS, 16 B/lane; LDS dest = wave-uniform base + lane*16
__device__ __forceinline__ void gld16(const bf16_t* g, bf16_t* l) {
    __builtin_amdgcn_global_load_lds(
        (const __attribute__((address_space(1))) void*)g,
        (__attribute__((address_space(3))) void*)l, 16, 0, 0);
}

// ---------------------------------------------------------------------------
// fp32 -> bf16 pre-convert, WEIGHTS ONLY (4 x 1M elements)
// ---------------------------------------------------------------------------
__global__ __launch_bounds__(256) void cvt_w(
    const float* __restrict__ Wq, const float* __restrict__ Wk,
    const float* __restrict__ Wv, const float* __restrict__ Wo,
    bf16_t* __restrict__ Wqb, bf16_t* __restrict__ Wkb,
    bf16_t* __restrict__ Wvb, bf16_t* __restrict__ Wob)
{
    const float* s; bf16_t* d;
    switch (blockIdx.y) {
        case 0:  s = Wq; d = Wqb; break;
        case 1:  s = Wk; d = Wkb; break;
        case 2:  s = Wv; d = Wvb; break;
        default: s = Wo; d = Wob; break;
    }
    size_t e = ((size_t)blockIdx.x * 256 + threadIdx.x) * 8;
    if (e >= WELT) return;
    f32x4 a = *(const f32x4*)(s + e);
    f32x4 b = *(const f32x4*)(s + e + 4);
    bf16x8 o;
    #pragma unroll
    for (int i = 0; i < 4; ++i) { o[i] = (bf16_t)a[i]; o[4 + i] = (bf16_t)b[i]; }
    *(bf16x8*)(d + e) = o;
}

// ---------------------------------------------------------------------------
// Fused QKV projection: BM=64, BN=128, BK=64 -> grid (64,8,3)=1536 blocks.
// A read DIRECTLY as fp32: prefetched to regs during compute (T14), written
// to XOR-swizzled As (T2). W async gld16 (bf16, linear LDS).
// z=0: Qp=(q@Wq^T+bq)*(0.125*log2e) ; z=1: Kp ; z=2: Vt (transposed store)
// XCD swizzle: XCD k owns x in [8k,8k+8) for all y (A-panel L2 locality).
// ---------------------------------------------------------------------------
#define BMQ 64
#define BNQ 128
#define BKG 64
#define LDCQ 68

// issue A loads for k-step K0 into ax/ay (consumed by WRITEA next phase)
#define LOADA(K0)                                                              \
do {                                                                           \
    _Pragma("unroll")                                                          \
    for (int j = 0; j < 2; ++j) {                                              \
        int r0 = wave * 16 + j * 8;                                            \
        const float* ap = A + (size_t)(bm + r0 + srow) * DD + (K0) + scol;     \
        ax[j] = *(const f32x4*)ap;                                             \
        ay[j] = *(const f32x4*)(ap + 4);                                       \
    }                                                                          \
} while (0)

// cvt + swizzled LDS write: elem offset = row*64 + (scol ^ ((row&7)<<3))
#define WRITEA()                                                               \
do {                                                                           \
    _Pragma("unroll")                                                          \
    for (int j = 0; j < 2; ++j) {                                              \
        int r0 = wave * 16 + j * 8;                                            \
        bf16x8 o;                                                              \
        _Pragma("unroll")                                                      \
        for (int i = 0; i < 4; ++i) {                                          \
            o[i] = (bf16_t)ax[j][i]; o[4 + i] = (bf16_t)ay[j][i];              \
        }                                                                      \
        *(bf16x8*)(&As[0][0] + (size_t)(r0 + srow) * BKG                       \
                   + (scol ^ (srow << 3))) = o;                                \
    }                                                                          \
} while (0)

__global__ __launch_bounds__(256) void gemm_qkv6(
    const float* __restrict__ qf32, const float* __restrict__ kf32, const float* __restrict__ vf32,
    const bf16_t* __restrict__ Wqb, const bf16_t* __restrict__ Wkb, const bf16_t* __restrict__ Wvb,
    const float* __restrict__ bq, const float* __restrict__ bk, const float* __restrict__ bv,
    bf16_t* __restrict__ Qp, bf16_t* __restrict__ Kp, bf16_t* __restrict__ Vt)
{
    const int z = blockIdx.z;
    const float*  A    = (z == 0) ? qf32 : (z == 1) ? kf32 : vf32;
    const bf16_t* W    = (z == 0) ? Wqb  : (z == 1) ? Wkb  : Wvb;
    const float*  bias = (z == 0) ? bq   : (z == 1) ? bk   : bv;

    // union: As[64][64] (8KB) + Bs[128][64] (16KB) = 24KB vs Ct[128][68] 17.4KB
    __shared__ __align__(16) bf16_t smem[(BMQ + BNQ) * BKG];
    bf16_t (*As)[BKG]  = (bf16_t(*)[BKG])smem;
    bf16_t (*Bs)[BKG]  = (bf16_t(*)[BKG])(smem + BMQ * BKG);
    bf16_t (*Ct)[LDCQ] = (bf16_t(*)[LDCQ])smem;

    const int tid  = threadIdx.x;
    const int wave = tid >> 6;
    const int lane = tid & 63;
    const int quad = lane >> 4;
    const int c16  = lane & 15;

    // XCD-aware remap: f = per-slice dispatch id (x fastest, 512 wgs).
    // f2 = (f%8)*64 + f/8 -> XCD k gets f2 in [64k,64k+64):
    // x = f2>>3 in [8k,8k+8) (A panels), y = f2&7.
    const int f  = blockIdx.x + 64 * blockIdx.y;
    const int f2 = (f & 7) * 64 + (f >> 3);
    const int bm = (f2 >> 3) * BMQ;
    const int bn = (f2 & 7) * BNQ;

    const int wm = (wave >> 1) * 32;
    const int wn = (wave & 1) * 64;

    const int srow = lane >> 3;        // 0..7 within an 8-row chunk
    const int scol = (lane & 7) * 8;   // 0..56
    const int swzA = (c16 & 7) << 3;   // read-side row XOR (row&7 == c16&7)

    f32x4 acc[2][4] = {};
    f32x4 ax[2], ay[2];                // A prefetch registers (one k-step)

    LOADA(0);
    for (int k0 = 0; k0 < DD; k0 += BKG) {
        __syncthreads();   // compute(k-1) done; A(k) regs arrived (overlapped)
        WRITEA();
        #pragma unroll
        for (int j = 0; j < 4; ++j) {
            int r0 = wave * 32 + j * 8;
            gld16(W + (size_t)(bn + r0 + srow) * DD + k0 + scol, &Bs[r0][0]);
        }
        __syncthreads();   // staging complete (drains vm+lgkm)

        if (k0 + BKG < DD) LOADA(k0 + BKG);   // issue early; lands during MFMA

        #pragma unroll
        for (int ks = 0; ks < 2; ++ks) {
            bf16x8 af[2], bfr[4];
            #pragma unroll
            for (int tm = 0; tm < 2; ++tm)
                af[tm] = *(const bf16x8*)(&As[0][0]
                    + (size_t)(wm + tm * 16 + c16) * BKG
                    + ((ks * 32 + quad * 8) ^ swzA));
            #pragma unroll
            for (int tn = 0; tn < 4; ++tn)
                bfr[tn] = *(const bf16x8*)(&Bs[wn + tn * 16 + c16][ks * 32 + quad * 8]);
            #pragma unroll
            for (int tm = 0; tm < 2; ++tm)
                #pragma unroll
                for (int tn = 0; tn < 4; ++tn)
                    acc[tm][tn] = __builtin_amdgcn_mfma_f32_16x16x32_bf16(
                        af[tm], bfr[tn], acc[tm][tn], 0, 0, 0);
        }
    }

    float bia[4];
    #pragma unroll
    for (int tn = 0; tn < 4; ++tn)
        bia[tn] = bias[bn + wn + tn * 16 + c16];

    if (z < 2) {
        // Q carries 1/sqrt(DK) * log2(e) so attention can use exp2
        const float osc = (z == 0) ? 0.125f * 1.4426950408889634f : 1.0f;
        bf16_t* C = (z == 0) ? Qp : Kp;
        #pragma unroll
        for (int tm = 0; tm < 2; ++tm)
            #pragma unroll
            for (int r = 0; r < 4; ++r) {
                size_t base = (size_t)(bm + wm + tm * 16 + quad * 4 + r) * DD;
                #pragma unroll
                for (int tn = 0; tn < 4; ++tn)
                    C[base + bn + wn + tn * 16 + c16] =
                        (bf16_t)((acc[tm][tn][r] + bia[tn]) * osc);
            }
    } else {
        __syncthreads();
        #pragma unroll
        for (int tm = 0; tm < 2; ++tm)
            #pragma unroll
            for (int tn = 0; tn < 4; ++tn) {
                bf16x4 pk;
                #pragma unroll
                for (int r = 0; r < 4; ++r)
                    pk[r] = (bf16_t)(acc[tm][tn][r] + bia[tn]);
                *(bf16x4*)(&Ct[wn + tn * 16 + c16][wm + tm * 16 + quad * 4]) = pk;
            }
        __syncthreads();
        const int b_    = bm >> 11;
        const int sbase = bm & (SS - 1);
        #pragma unroll
        for (int p = 0; p < 4; ++p) {
            int col = p * 32 + (tid >> 3);       // 0..127
            int si  = (tid & 7) * 8;             // 0..56 (64-wide stripe)
            size_t rowoff = (size_t)(b_ * 1024 + bn + col) * SS + sbase;
            *(bf16x8*)(&Vt[rowoff + si]) = *(const bf16x8*)(&Ct[col][si]);
        }
    }
}

// ---------------------------------------------------------------------------
// Output projection: BM=64, BN=64, BK=64 -> grid (64,16)=1024 blocks
// (4 blocks/CU, 16 waves/CU). Wave tile 32x32. XCD swizzle: XCD k owns
// x in [8k,8k+8) for all y (A-panel locality).
// ---------------------------------------------------------------------------
__global__ __launch_bounds__(256) void gemm_out(
    const bf16_t* __restrict__ A,    // Xa [M,K]
    const bf16_t* __restrict__ W,    // Wob [N,K]
    const float* __restrict__ bias,
    float* __restrict__ C)
{
    __shared__ __align__(16) bf16_t As[64][BKG];
    __shared__ __align__(16) bf16_t Bs[64][BKG];

    const int tid  = threadIdx.x;
    const int wave = tid >> 6;
    const int lane = tid & 63;
    const int quad = lane >> 4;
    const int c16  = lane & 15;

    // f = dispatch id (x fastest, 1024 wgs). f2 = (f%8)*128 + f/8:
    // XCD k gets f2 in [128k,128k+128): x = f2>>4 in [8k,8k+8), y = f2&15.
    const int f  = blockIdx.x + 64 * blockIdx.y;
    const int f2 = (f & 7) * 128 + (f >> 3);
    const int bm = (f2 >> 4) * 64;
    const int bn = (f2 & 15) * 64;

    const int wm = (wave >> 1) * 32;
    const int wn = (wave & 1) * 32;

    const int srow = lane >> 3;
    const int scol = (lane & 7) * 8;

    f32x4 acc[2][2] = {};

    for (int k0 = 0; k0 < DD; k0 += BKG) {
        __syncthreads();
        #pragma unroll
        for (int j = 0; j < 2; ++j) {
            int r0 = wave * 16 + j * 8;
            gld16(A + (size_t)(bm + r0 + srow) * DD + k0 + scol, &As[r0][0]);
            gld16(W + (size_t)(bn + r0 + srow) * DD + k0 + scol, &Bs[r0][0]);
        }
        __syncthreads();

        #pragma unroll
        for (int ks = 0; ks < 2; ++ks) {
            bf16x8 af[2], bfr[2];
            #pragma unroll
            for (int tm = 0; tm < 2; ++tm)
                af[tm] = *(const bf16x8*)(&As[wm + tm * 16 + c16][ks * 32 + quad * 8]);
            #pragma unroll
            for (int tn = 0; tn < 2; ++tn)
                bfr[tn] = *(const bf16x8*)(&Bs[wn + tn * 16 + c16][ks * 32 + quad * 8]);
            #pragma unroll
            for (int tm = 0; tm < 2; ++tm)
                #pragma unroll
                for (int tn = 0; tn < 2; ++tn)
                    acc[tm][tn] = __builtin_amdgcn_mfma_f32_16x16x32_bf16(
                        af[tm], bfr[tn], acc[tm][tn], 0, 0, 0);
        }
    }

    float bia[2];
    #pragma unroll
    for (int tn = 0; tn < 2; ++tn)
        bia[tn] = bias[bn + wn + tn * 16 + c16];

    #pragma unroll
    for (int tm = 0; tm < 2; ++tm)
        #pragma unroll
        for (int r = 0; r < 4; ++r) {
            size_t base = (size_t)(bm + wm + tm * 16 + quad * 4 + r) * DD;
            #pragma unroll
            for (int tn = 0; tn < 2; ++tn)
                C[base + bn + wn + tn * 16 + c16] = acc[tm][tn][r] + bia[tn];
        }
}

// ---------------------------------------------------------------------------
// Split-K flash attention (r17 structure, unchanged), paired qtiles.
// Grid = dim3(1024): bh = (id%8)*4 + id/256 (XCD-resident), pair = (id>>3)&31.
// ---------------------------------------------------------------------------
#define LDPS 40   // P row stride (bf16): rows=q(32), cols=key(32)
#define LDCF 68   // combine row stride (fp32)

#define LOADK(KF, UU)                                                          \
do {                                                                           \
    const int kb_ = (UU) * 32;                                                 \
    const bf16_t* kp0 = Kb + (size_t)(kb_ + c16) * DD;                         \
    const bf16_t* kp1 = Kb + (size_t)(kb_ + 16 + c16) * DD;                    \
    KF[0][0] = *(const bf16x8*)(kp0 + quad * 8);                               \
    KF[0][1] = *(const bf16x8*)(kp0 + 32 + quad * 8);                          \
    KF[1][0] = *(const bf16x8*)(kp1 + quad * 8);                               \
    KF[1][1] = *(const bf16x8*)(kp1 + 32 + quad * 8);                          \
} while (0)

// r12-style step: QK[u] on KFC | prefetch K[u+4]->KFN | load V[u] | exp2 +
// packed P store | lgkmcnt(0) | PV[u] same step.
#define ATTN_STEP(UU, KFC, KFN)                                                \
do {                                                                           \
    const int kb_ = (UU) * 32;                                                 \
    f32x4 sc_[2][2];                                                           \
    __builtin_amdgcn_s_setprio(1);                                             \
    _Pragma("unroll")                                                          \
    for (int tm = 0; tm < 2; ++tm)                                             \
        _Pragma("unroll")                                                      \
        for (int ct = 0; ct < 2; ++ct) {                                       \
            f32x4 s_ = {};                                                     \
            s_ = __builtin_amdgcn_mfma_f32_16x16x32_bf16(                      \
                     KFC[ct][0], qf[tm][0], s_, 0, 0, 0);                      \
            s_ = __builtin_amdgcn_mfma_f32_16x16x32_bf16(                      \
                     KFC[ct][1], qf[tm][1], s_, 0, 0, 0);                      \
            sc_[tm][ct] = s_;                                                  \
        }                                                                      \
    __builtin_amdgcn_s_setprio(0);                                             \
    if ((UU) + 4 < U) LOADK(KFN, (UU) + 4);                                    \
    bf16x8 vf_[4];                                                             \
    _Pragma("unroll")                                                          \
    for (int tn = 0; tn < 4; ++tn)                                             \
        vf_[tn] = *(const bf16x8*)(Vb + (size_t)(tn * 16 + c16) * SS           \
                                   + kb_ + quad * 8);                          \
    const bool needmask_ = (kb_ == qbase);                                     \
    _Pragma("unroll")                                                          \
    for (int tm = 0; tm < 2; ++tm) {                                           \
        const int qrow_ = qbase + tm * 16 + c16;                               \
        _Pragma("unroll")                                                      \
        for (int ct = 0; ct < 2; ++ct) {                                       \
            bf16x4 w_;                                                         \
            _Pragma("unroll")                                                  \
            for (int r = 0; r < 4; ++r) {                                      \
                float s_ = sc_[tm][ct][r];                                     \
                if (needmask_ && (kb_ + ct * 16 + quad * 4 + r > qrow_))       \
                    s_ = -1e9f;                                                \
                float p_ = __builtin_amdgcn_exp2f(s_);                         \
                lsum2[tm] += p_;                                               \
                w_[r] = (bf16_t)p_;                                            \
            }                                                                  \
            *(bf16x4*)(pw + tm * 16 * LDPS + ct * 16) = w_;                    \
        }                                                                      \
    }                                                                          \
    asm volatile("s_waitcnt lgkmcnt(0)" ::: "memory");                         \
    __builtin_amdgcn_s_setprio(1);                                             \
    _Pragma("unroll")                                                          \
    for (int tm = 0; tm < 2; ++tm) {                                           \
        bf16x8 pa_ = *(const bf16x8*)(pr + tm * 16 * LDPS);                    \
        _Pragma("unroll")                                                      \
        for (int tn = 0; tn < 4; ++tn)                                         \
            oacc[tm][tn] = __builtin_amdgcn_mfma_f32_16x16x32_bf16(            \
                pa_, vf_[tn], oacc[tm][tn], 0, 0, 0);                          \
    }                                                                          \
    __builtin_amdgcn_s_setprio(0);                                             \
} while (0)

__global__ __launch_bounds__(256) void attn_fwd11(
    const bf16_t* __restrict__ Q,   // [B,S,D] (pre-scaled by 0.125*log2e)
    const bf16_t* __restrict__ K,   // [B,S,D]
    const bf16_t* __restrict__ Vt,  // [(b*1024 + h*64 + dk)][s]
    bf16_t* __restrict__ O)         // [B,S,D]
{
    const int flat = blockIdx.x;
    const int bh   = (flat & 7) * 4 + (flat >> 8);   // XCD-resident heads
    const int pair = (flat >> 3) & 31;
    const int b = bh >> 4;
    const int h = bh & 15;

    const int wave = threadIdx.x >> 6;
    const int lane = threadIdx.x & 63;
    const int quad = lane >> 4;
    const int c16  = lane & 15;

    // union: Ps[4][32][LDPS] bf16 (10.2 KB) / Cf[4][16][LDCF] fp32 (17.4 KB)
    __shared__ __align__(16) unsigned char smraw[4 * 16 * LDCF * 4];
    bf16_t (*Ps)[32][LDPS] = (bf16_t(*)[32][LDPS])smraw;
    float  (*Cf)[16][LDCF] = (float(*)[16][LDCF])smraw;
    __shared__ float Ls[4][32];

    const bf16_t* Kb = K  + (size_t)b * SS * DD + h * DKK;
    const bf16_t* Vb = Vt + (size_t)(b * 1024 + h * DKK) * SS;

    // fixed per-lane LDS addresses (immediate offsets inside the loop)
    bf16_t*       pw = &Ps[wave][c16][quad * 4];   // + tm*16*LDPS + ct*16
    const bf16_t* pr = &Ps[wave][c16][quad * 8];   // + tm*16*LDPS

    for (int t = 0; t < 2; ++t) {
        const int qt    = (t == 0) ? (63 - pair) : pair;   // heavy tile first
        const int qbase = qt * 32;
        const int U     = qt + 1;          // 32-key units

        // Q fragments (B operand of swapped MFMA): rows qbase..qbase+31
        bf16x8 qf[2][2];
        #pragma unroll
        for (int tm = 0; tm < 2; ++tm) {
            const bf16_t* qp = Q + ((size_t)b * SS + qbase + tm * 16 + c16) * DD + h * DKK;
            qf[tm][0] = *(const bf16x8*)(qp + quad * 8);
            qf[tm][1] = *(const bf16x8*)(qp + 32 + quad * 8);
        }

        f32x4 oacc[2][4] = {};
        float lsum2[2] = {0.f, 0.f};

        bf16x8 kfA[2][2], kfB[2][2];   // K fragment double buffer [ct][kstep]

        {
            int u = wave;
            if (u < U) {
                LOADK(kfA, u);
                for (;;) {
                    ATTN_STEP(u, kfA, kfB); u += 4;
                    if (u >= U) break;
                    ATTN_STEP(u, kfB, kfA); u += 4;
                    if (u >= U) break;
                }
            }
        }

        // ---- per-wave row sums (reduce over quads) -> Ls ----
        #pragma unroll
        for (int tm = 0; tm < 2; ++tm) {
            float l = lsum2[tm];
            l += __shfl_xor(l, 16, 64);
            l += __shfl_xor(l, 32, 64);
            if (lane < 16) Ls[wave][tm * 16 + lane] = l;
        }

        // ---- combine partials: two tm-passes through Cf (aliases Ps) ----
        const int row = threadIdx.x >> 4;        // 0..15
        const int col = (threadIdx.x & 15) * 4;  // 0..60
        #pragma unroll
        for (int tm = 0; tm < 2; ++tm) {
            __syncthreads();   // tm=0: unit loops done (Ps free); tm=1: pass-0 reads done
            #pragma unroll
            for (int tn = 0; tn < 4; ++tn)
                #pragma unroll
                for (int r = 0; r < 4; ++r)
                    Cf[wave][quad * 4 + r][tn * 16 + c16] = oacc[tm][tn][r];
            __syncthreads();
            f32x4 ssum = {};
            #pragma unroll
            for (int p = 0; p < 4; ++p)
                ssum += *(const f32x4*)(&Cf[p][row][col]);
            float l = Ls[0][tm * 16 + row] + Ls[1][tm * 16 + row]
                    + Ls[2][tm * 16 + row] + Ls[3][tm * 16 + row];
            float inv = 1.0f / l;
            bf16x4 o;
            #pragma unroll
            for (int i = 0; i < 4; ++i) o[i] = (bf16_t)(ssum[i] * inv);
            *(bf16x4*)(&O[((size_t)b * SS + qbase + tm * 16 + row) * DD + h * DKK + col]) = o;
        }
        __syncthreads();   // tile end: Ps/Cf/Ls reusable by next tile
    }
}

// ---------------------------------------------------------------------------
extern "C" void kernel_launch(void* const* d_in, const int* in_sizes, int n_in,
                              void* d_out, int out_size, void* d_ws, size_t ws_size,
                              hipStream_t stream) {
    (void)in_sizes; (void)n_in; (void)out_size; (void)d_ws; (void)ws_size;
    const float* q  = (const float*)d_in[0];
    const float* k  = (const float*)d_in[1];
    const float* v  = (const float*)d_in[2];
    const float* Wq = (const float*)d_in[4];
    const float* bq = (const float*)d_in[5];
    const float* Wk = (const float*)d_in[6];
    const float* bk = (const float*)d_in[7];
    const float* Wv = (const float*)d_in[8];
    const float* bv = (const float*)d_in[9];
    const float* Wo = (const float*)d_in[10];
    const float* bo = (const float*)d_in[11];

    bf16_t* ws;
    hipGetSymbolAddress((void**)&ws, HIP_SYMBOL(g_ws));
    bf16_t* Qp  = ws;
    bf16_t* Kp  = Qp + NELT;
    bf16_t* Vt  = Kp + NELT;
    bf16_t* Xa  = Vt + NELT;
    bf16_t* Wqb = Xa + NELT;
    bf16_t* Wkb = Wqb + WELT;
    bf16_t* Wvb = Wkb + WELT;
    bf16_t* Wob = Wvb + WELT;

    cvt_w<<<dim3(512, 4), 256, 0, stream>>>(Wq, Wk, Wv, Wo,
                                            Wqb, Wkb, Wvb, Wob);

    gemm_qkv6<<<dim3(MM / BMQ, DD / BNQ, 3), 256, 0, stream>>>(
        q, k, v, Wqb, Wkb, Wvb, bq, bk, bv, Qp, Kp, Vt);

    attn_fwd11<<<dim3(1024), 256, 0, stream>>>(Qp, Kp, Vt, Xa);

    gemm_out<<<dim3(64, 16), 256, 0, stream>>>(Xa, Wob, bo, (float*)d_out);
}